// Round 4
// baseline (163.761 us; speedup 1.0000x reference)
//
#include <hip/hip_runtime.h>
#include <hip/hip_bf16.h>

#define B_ 8
#define H_ 56
#define W_ 56
#define C_ 384
#define HEADS_ 12
#define NPIX (B_*H_*W_)      // 25088
#define NPAD 1408            // 1356 padded to 11*128
#define KDIM 384

typedef unsigned short u16;
typedef __attribute__((ext_vector_type(4))) float f32x4;
typedef __attribute__((ext_vector_type(8))) short bf16x8;
typedef __attribute__((ext_vector_type(8))) unsigned short u16x8;

#define GLDS16(g, l)                                                            \
    __builtin_amdgcn_global_load_lds(                                           \
        (const __attribute__((address_space(1))) void*)(g),                     \
        (__attribute__((address_space(3))) void*)(l), 16, 0, 0)

__device__ __forceinline__ float bf2f(u16 u) {
    union { unsigned int uu; float f; } cv; cv.uu = ((unsigned)u) << 16; return cv.f;
}
__device__ __forceinline__ u16 f2bf(float f) {
    __hip_bfloat16 hb = __float2bfloat16(f);
    return *reinterpret_cast<u16*>(&hb);
}

// ---------------- pack: fp32 -> bf16 (x vectorized, [Wv;Wa;0], Wo) ----------------
__global__ void pack_kernel(const float* __restrict__ x, const float* __restrict__ Wv,
                            const float* __restrict__ Wa, const float* __restrict__ Wo,
                            u16* __restrict__ xb, __hip_bfloat16* __restrict__ wcat,
                            __hip_bfloat16* __restrict__ wob) {
    const int NX8 = NPIX * C_ / 8;   // 1204224 (x in 8-float chunks)
    const int NW = NPAD * KDIM;      // 540672
    const int NO = C_ * C_;          // 147456
    const int total = NX8 + NW + NO;
    for (int idx = blockIdx.x * blockDim.x + threadIdx.x; idx < total;
         idx += gridDim.x * blockDim.x) {
        if (idx < NX8) {
            float4 a = ((const float4*)x)[idx * 2];
            float4 b = ((const float4*)x)[idx * 2 + 1];
            u16x8 o;
            o[0] = f2bf(a.x); o[1] = f2bf(a.y); o[2] = f2bf(a.z); o[3] = f2bf(a.w);
            o[4] = f2bf(b.x); o[5] = f2bf(b.y); o[6] = f2bf(b.z); o[7] = f2bf(b.w);
            ((u16x8*)xb)[idx] = o;
        } else if (idx < NX8 + NW) {
            int t = idx - NX8;
            int o = t / KDIM;
            float v = 0.f;
            if (o < 384) v = Wv[t];
            else if (o < 1356) v = Wa[t - 147456];
            wcat[t] = __float2bfloat16(v);
        } else {
            int t = idx - NX8 - NW;
            wob[t] = __float2bfloat16(Wo[t]);
        }
    }
}

// ---------------- 256x256 phase-interleaved bf16 MFMA GEMM: C = A[M,K] * B[N,K]^T ----
// 512 threads (8 waves, 2M x 4N), BK=32, 4-slot LDS ring (128KB dynamic), counted vmcnt.
// Swizzle: LDS(row, slot) holds G(row, slot ^ (row&3)); gload_lds dest linear,
// source pre-swizzled (rule #21); ds_read applies same XOR -> conflict-free (R2-verified).
// B rows clamped to Nm1 (zero/pad rows); C stores masked to col < Nreal.

#define STAGE_A(rb_, t_) do {                                                       \
    _Pragma("unroll") for (int jj = 0; jj < 2; ++jj) {                              \
        int chunk = tid + jj * 512;                                                 \
        int rw = chunk >> 2, sl = chunk & 3;                                        \
        int col = ((sl ^ (rw & 3)) << 3) + (t_) * 32;                               \
        GLDS16(&A[(size_t)(bm * 256 + rw) * Kd + col],                              \
               LA + (rb_) * 8192 + (wid * 64 + jj * 512) * 8);                      \
    } } while (0)

#define STAGE_B(rb_, t_) do {                                                       \
    _Pragma("unroll") for (int jj = 0; jj < 2; ++jj) {                              \
        int chunk = tid + jj * 512;                                                 \
        int rw = chunk >> 2, sl = chunk & 3;                                        \
        int br = bn * 256 + rw; if (br > Nm1) br = Nm1;                             \
        int col = ((sl ^ (rw & 3)) << 3) + (t_) * 32;                               \
        GLDS16(&Bw[(size_t)br * Kd + col],                                          \
               LB + (rb_) * 8192 + (wid * 64 + jj * 512) * 8);                      \
    } } while (0)

template<int OUT_BF16>
__global__ __launch_bounds__(512, 2) void gemm256(const u16* __restrict__ A,
                                                  const u16* __restrict__ Bw,
                                                  void* __restrict__ Cout,
                                                  int Nreal, int Kd, int gridN,
                                                  int q, int r) {
    extern __shared__ u16 lds[];
    u16* LA = lds;            // 4 slots x 8192 u16 (256 rows x 32 cols each)
    u16* LB = lds + 32768;
    const int bid = blockIdx.x;
    const int xcd = bid & 7, ii = bid >> 3;
    const int logical = (xcd < r) ? xcd * (q + 1) + ii : r * (q + 1) + (xcd - r) * q + ii;
    const int bm = logical / gridN, bn = logical - bm * gridN;
    const int tid = threadIdx.x;
    const int lane = tid & 63, wid = tid >> 6;
    const int wm = wid >> 2, wn = wid & 3;     // wave grid 2M x 4N
    const int fr = lane & 15, kg = lane >> 4;
    const int Nm1 = Nreal - 1;
    const int NT = Kd >> 5;                    // K-tiles of 32 (= 12 for K=384)
    f32x4 acc[8][4] = {};

    // prologue: stage tiles 0,1,2; force tile 0 landed (vmcnt(8) leaves A1,B1,A2,B2)
    STAGE_A(0, 0); STAGE_B(0, 0);
    STAGE_A(1, 1); STAGE_B(1, 1);
    STAGE_A(2, 2); STAGE_B(2, 2);
    asm volatile("s_waitcnt vmcnt(8)" ::: "memory");
    __builtin_amdgcn_s_barrier();

#pragma unroll 4
    for (int t = 0; t < NT; ++t) {
        const int rb = t & 3;
        const u16* la = LA + rb * 8192;
        const u16* lb = LB + rb * 8192;
        bf16x8 af[4], bq[4];
        // ---- phase 1: quad mq0 (wave rows 0-63) ----
#pragma unroll
        for (int m = 0; m < 4; ++m) {
            int row = wm * 128 + m * 16 + fr;
            af[m] = *(const bf16x8*)(la + row * 32 + ((kg ^ (row & 3)) << 3));
        }
#pragma unroll
        for (int n = 0; n < 4; ++n) {
            int row = wn * 64 + n * 16 + fr;
            bq[n] = *(const bf16x8*)(lb + row * 32 + ((kg ^ (row & 3)) << 3));
        }
        if (t + 3 < NT) STAGE_A((t + 3) & 3, t + 3);
        __builtin_amdgcn_s_barrier();
        __builtin_amdgcn_sched_barrier(0);
        __builtin_amdgcn_s_setprio(1);
#pragma unroll
        for (int m = 0; m < 4; ++m)
#pragma unroll
            for (int n = 0; n < 4; ++n)
                acc[m][n] = __builtin_amdgcn_mfma_f32_16x16x32_bf16(af[m], bq[n], acc[m][n], 0, 0, 0);
        __builtin_amdgcn_s_setprio(0);
        __builtin_amdgcn_sched_barrier(0);
        __builtin_amdgcn_s_barrier();
        // ---- phase 2: quad mq1 (wave rows 64-127), B regs reused ----
        bf16x8 ag[4];
#pragma unroll
        for (int m = 0; m < 4; ++m) {
            int row = wm * 128 + 64 + m * 16 + fr;
            ag[m] = *(const bf16x8*)(la + row * 32 + ((kg ^ (row & 3)) << 3));
        }
        if (t + 3 < NT) STAGE_B((t + 3) & 3, t + 3);
        // counted waits: force tile t+1 landed before its reads next phase-pair.
        if (t < NT - 3)       asm volatile("s_waitcnt vmcnt(6)" ::: "memory");
        else if (t == NT - 3) asm volatile("s_waitcnt vmcnt(4)" ::: "memory");
        else if (t == NT - 2) asm volatile("s_waitcnt vmcnt(0)" ::: "memory");
        __builtin_amdgcn_s_barrier();
        __builtin_amdgcn_sched_barrier(0);
        __builtin_amdgcn_s_setprio(1);
#pragma unroll
        for (int m = 0; m < 4; ++m)
#pragma unroll
            for (int n = 0; n < 4; ++n)
                acc[4 + m][n] = __builtin_amdgcn_mfma_f32_16x16x32_bf16(ag[m], bq[n], acc[4 + m][n], 0, 0, 0);
        __builtin_amdgcn_s_setprio(0);
        __builtin_amdgcn_sched_barrier(0);
        __builtin_amdgcn_s_barrier();
    }

    // epilogue: C/D layout col=lane&15, row=(lane>>4)*4+j [verified m89/m91]
    const int r0 = bm * 256 + wm * 128 + kg * 4;
    const int c0 = bn * 256 + wn * 64 + fr;
#pragma unroll
    for (int m = 0; m < 8; ++m)
#pragma unroll
        for (int n = 0; n < 4; ++n) {
            int col = c0 + n * 16;
            if (col < Nreal) {
#pragma unroll
                for (int j = 0; j < 4; ++j) {
                    size_t off = (size_t)(r0 + m * 16 + j) * Nreal + col;
                    if (OUT_BF16) ((__hip_bfloat16*)Cout)[off] = __float2bfloat16(acc[m][n][j]);
                    else          ((float*)Cout)[off] = acc[m][n][j];
                }
            }
        }
}

// ---------------- fused softmax + collapse to 25 taps ----------------
__global__ __launch_bounds__(256) void attn_w25(const __hip_bfloat16* __restrict__ va,
                                                u16* __restrict__ w25b) {
    int idx = blockIdx.x * 256 + threadIdx.x;
    if (idx >= NPIX * HEADS_) return;
    int pix = idx / 12, h = idx - pix * 12;
    int b = pix / 3136, rs = pix - b * 3136;
    int r = rs / 56, s = rs - r * 56;
    const u16* vap = (const u16*)va;
    float w[25];
#pragma unroll
    for (int t = 0; t < 25; ++t) w[t] = 0.f;
    const float SC = 0.17677669529663687f;  // 1/sqrt(32)
#pragma unroll
    for (int i = 0; i < 3; ++i) {
        int cy = r + 1 - i;
        if ((unsigned)cy >= (unsigned)H_) continue;
#pragma unroll
        for (int j = 0; j < 3; ++j) {
            int cx = s + 1 - j;
            if ((unsigned)cx >= (unsigned)W_) continue;
            const u16* ap = vap + (size_t)(b * 3136 + cy * 56 + cx) * NPAD + C_ + h * 81 + (i * 3 + j) * 9;
            float aq[9];
            float mx = -1e30f;
#pragma unroll
            for (int q = 0; q < 9; ++q) { aq[q] = bf2f(ap[q]); mx = fmaxf(mx, aq[q]); }
            float ssum = 0.f;
#pragma unroll
            for (int q = 0; q < 9; ++q) { aq[q] = __expf((aq[q] - mx) * SC); ssum += aq[q]; }
            float inv = 1.f / ssum;
#pragma unroll
            for (int qi = 0; qi < 3; ++qi)
#pragma unroll
                for (int qj = 0; qj < 3; ++qj)
                    w[(qi - i + 2) * 5 + (qj - j + 2)] += aq[qi * 3 + qj] * inv;
        }
    }
    u16* wp = w25b + (size_t)pix * 300 + h;
#pragma unroll
    for (int t = 0; t < 25; ++t) wp[t * 12] = f2bf(w[t]);
}

// ---------------- fold: y[pix][c] = sum_taps w25[tap][head(c)] * v[tap_pixel][c] ----------------
__global__ __launch_bounds__(384) void fold_gather(const __hip_bfloat16* __restrict__ va,
                                                   const u16* __restrict__ w25b,
                                                   __hip_bfloat16* __restrict__ yb) {
    __shared__ float wls[8][300];
    const int tid = threadIdx.x;
    const int pix0 = blockIdx.x * 8;
    for (int i = tid; i < 2400; i += 384)
        wls[i / 300][i % 300] = bf2f(w25b[(size_t)pix0 * 300 + i]);
    __syncthreads();
    const int g = tid / 48, t = tid - g * 48;
    const int c0 = t * 8, hh = t >> 2;
    const int pix = pix0 + g;
    const int b = pix / 3136, rs = pix - b * 3136;
    const int r = rs / 56, s = rs - r * 56;
    const u16* vap = (const u16*)va;
    float acc[8];
#pragma unroll
    for (int e = 0; e < 8; ++e) acc[e] = 0.f;
    const float* wp = &wls[g][hh];
#pragma unroll
    for (int dy = -2; dy <= 2; ++dy) {
        int py = r + dy;
        if ((unsigned)py >= (unsigned)H_) continue;
#pragma unroll
        for (int dx = -2; dx <= 2; ++dx) {
            int px = s + dx;
            if ((unsigned)px >= (unsigned)W_) continue;
            float w = wp[((dy + 2) * 5 + (dx + 2)) * 12];
            u16x8 v = *(const u16x8*)(vap + (size_t)(b * 3136 + py * 56 + px) * NPAD + c0);
#pragma unroll
            for (int e = 0; e < 8; ++e) acc[e] += w * bf2f(v[e]);
        }
    }
    u16x8 o;
#pragma unroll
    for (int e = 0; e < 8; ++e) o[e] = f2bf(acc[e]);
    *(u16x8*)((u16*)yb + (size_t)pix * C_ + c0) = o;
}

// ---------------- launch ----------------
extern "C" void kernel_launch(void* const* d_in, const int* in_sizes, int n_in,
                              void* d_out, int out_size, void* d_ws, size_t ws_size,
                              hipStream_t stream) {
    const float* x  = (const float*)d_in[0];
    const float* Wv = (const float*)d_in[1];
    const float* Wa = (const float*)d_in[2];
    const float* Wo = (const float*)d_in[3];
    char* ws = (char*)d_ws;
    // ws layout (bytes):
    //   xb/W25b @ 0        : 19267584 (xb dead after gemm1; w25b reuses)
    //   wcat @ 19267584    : 1081344
    //   wob  @ 20348928    : 294912
    //   va   @ 20643840    : 70647808
    //   yb   @ 91291648    : 19267584   (end: 110559232)
    u16*            xb   = (u16*)(ws);
    u16*            w25b = (u16*)(ws);
    __hip_bfloat16* wcat = (__hip_bfloat16*)(ws + 19267584);
    __hip_bfloat16* wob  = (__hip_bfloat16*)(ws + 20348928);
    __hip_bfloat16* va   = (__hip_bfloat16*)(ws + 20643840);
    __hip_bfloat16* yb   = (__hip_bfloat16*)(ws + 91291648);

    hipLaunchKernelGGL(pack_kernel, dim3(2048), dim3(256), 0, stream,
                       x, Wv, Wa, Wo, xb, wcat, wob);

    // gemm1: M=25088 (98 tiles), N=1408 padded to 6x256; B rows clamped, C masked.
    {
        int gridN = 6, nwg = 98 * gridN;  // 588
        int q = nwg / 8, r = nwg % 8;
        hipLaunchKernelGGL(HIP_KERNEL_NAME(gemm256<1>), dim3(nwg), dim3(512), 131072, stream,
                           (const u16*)xb, (const u16*)wcat, (void*)va, NPAD, KDIM, gridN, q, r);
    }
    hipLaunchKernelGGL(attn_w25, dim3((NPIX * HEADS_ + 255) / 256), dim3(256), 0, stream,
                       va, w25b);
    hipLaunchKernelGGL(fold_gather, dim3(NPIX / 8), dim3(384), 0, stream, va, w25b, yb);
    // gemm2: N=384 padded to 2x256 tiles
    {
        int gridN = 2, nwg = 98 * gridN;  // 196
        int q = nwg / 8, r = nwg % 8;
        hipLaunchKernelGGL(HIP_KERNEL_NAME(gemm256<0>), dim3(nwg), dim3(512), 131072, stream,
                           (const u16*)yb, (const u16*)wob, d_out, C_, KDIM, gridN, q, r);
    }
}

// Round 5
// 159.249 us; speedup vs baseline: 1.0283x; 1.0283x over previous
//
#include <hip/hip_runtime.h>
#include <hip/hip_bf16.h>

#define B_ 8
#define H_ 56
#define W_ 56
#define C_ 384
#define HEADS_ 12
#define NPIX (B_*H_*W_)      // 25088
#define NPAD 1408            // 1356 padded to 11*128
#define KDIM 384

typedef unsigned short u16;
typedef __attribute__((ext_vector_type(4))) float f32x4;
typedef __attribute__((ext_vector_type(8))) short bf16x8;
typedef __attribute__((ext_vector_type(8))) unsigned short u16x8;

#define GLDS16(g, l)                                                            \
    __builtin_amdgcn_global_load_lds(                                           \
        (const __attribute__((address_space(1))) void*)(g),                     \
        (__attribute__((address_space(3))) void*)(l), 16, 0, 0)

__device__ __forceinline__ float bf2f(u16 u) {
    union { unsigned int uu; float f; } cv; cv.uu = ((unsigned)u) << 16; return cv.f;
}
__device__ __forceinline__ u16 f2bf(float f) {
    __hip_bfloat16 hb = __float2bfloat16(f);
    return *reinterpret_cast<u16*>(&hb);
}

// packed-pair LDS offset (u16 units) within one 256x32 tile (16KB):
// two BK=32 rows share one 128B line; 8x16B slots XOR-swizzled by line index.
__device__ __forceinline__ int foff(int row, int kg) {
    int lrow = row >> 1;
    int s = (((row & 1) << 2) | kg) ^ (lrow & 7);
    return (lrow << 6) + (s << 3);
}

// ---------------- pack: fp32 -> bf16 (x vectorized, [Wv;Wa;0], Wo) ----------------
__global__ void pack_kernel(const float* __restrict__ x, const float* __restrict__ Wv,
                            const float* __restrict__ Wa, const float* __restrict__ Wo,
                            u16* __restrict__ xb, __hip_bfloat16* __restrict__ wcat,
                            __hip_bfloat16* __restrict__ wob) {
    const int NX8 = NPIX * C_ / 8;   // 1204224 (x in 8-float chunks)
    const int NW = NPAD * KDIM;      // 540672
    const int NO = C_ * C_;          // 147456
    const int total = NX8 + NW + NO;
    for (int idx = blockIdx.x * blockDim.x + threadIdx.x; idx < total;
         idx += gridDim.x * blockDim.x) {
        if (idx < NX8) {
            float4 a = ((const float4*)x)[idx * 2];
            float4 b = ((const float4*)x)[idx * 2 + 1];
            u16x8 o;
            o[0] = f2bf(a.x); o[1] = f2bf(a.y); o[2] = f2bf(a.z); o[3] = f2bf(a.w);
            o[4] = f2bf(b.x); o[5] = f2bf(b.y); o[6] = f2bf(b.z); o[7] = f2bf(b.w);
            ((u16x8*)xb)[idx] = o;
        } else if (idx < NX8 + NW) {
            int t = idx - NX8;
            int o = t / KDIM;
            float v = 0.f;
            if (o < 384) v = Wv[t];
            else if (o < 1356) v = Wa[t - 147456];
            wcat[t] = __float2bfloat16(v);
        } else {
            int t = idx - NX8 - NW;
            wob[t] = __float2bfloat16(Wo[t]);
        }
    }
}

// ---------------- 256x256 phase-interleaved bf16 MFMA GEMM: C = A[M,K] * B[N,K]^T ----
// 512 threads (8 waves, 2M x 4N), BK=32, 4-slot LDS ring (128KB dynamic), counted vmcnt.
// LDS layout: packed-pair (two 32-col rows per 128B line, 8 slots, XOR line&7) ->
// 128B-stride + uniform 8-slot spread per wave read = R2's measured-zero-conflict class.
// Staging: linear gload_lds dest + inverse-permuted global source (rule #21).
// B rows clamped to Nm1 (pad rows); C stores masked to col < Nreal.

#define STAGE_A(rb_, t_) do {                                                       \
    _Pragma("unroll") for (int jj = 0; jj < 2; ++jj) {                              \
        int chunk = tid + jj * 512;            /* 0..1023 16B chunks */             \
        int lrow = chunk >> 3, sl = chunk & 7;                                      \
        int u = sl ^ (lrow & 7);                                                    \
        int grow = lrow * 2 + (u >> 2);                                             \
        int gcol = (u & 3) << 3;                                                    \
        GLDS16(&A[(size_t)(bm * 256 + grow) * Kd + (t_) * 32 + gcol],               \
               LA + (rb_) * 8192 + (wid * 64 + jj * 512) * 8);                      \
    } } while (0)

#define STAGE_B(rb_, t_) do {                                                       \
    _Pragma("unroll") for (int jj = 0; jj < 2; ++jj) {                              \
        int chunk = tid + jj * 512;                                                 \
        int lrow = chunk >> 3, sl = chunk & 7;                                      \
        int u = sl ^ (lrow & 7);                                                    \
        int grow = lrow * 2 + (u >> 2);                                             \
        int gcol = (u & 3) << 3;                                                    \
        int br = bn * 256 + grow; if (br > Nm1) br = Nm1;                           \
        GLDS16(&Bw[(size_t)br * Kd + (t_) * 32 + gcol],                             \
               LB + (rb_) * 8192 + (wid * 64 + jj * 512) * 8);                      \
    } } while (0)

template<int OUT_BF16>
__global__ __launch_bounds__(512, 2) void gemm256(const u16* __restrict__ A,
                                                  const u16* __restrict__ Bw,
                                                  void* __restrict__ Cout,
                                                  int Nreal, int Kd, int gridN,
                                                  int q, int r) {
    extern __shared__ u16 lds[];
    u16* LA = lds;            // 4 slots x 8192 u16 (256 rows x 32 cols each, packed-pair)
    u16* LB = lds + 32768;
    const int bid = blockIdx.x;
    const int xcd = bid & 7, ii = bid >> 3;
    const int logical = (xcd < r) ? xcd * (q + 1) + ii : r * (q + 1) + (xcd - r) * q + ii;
    const int bm = logical / gridN, bn = logical - bm * gridN;
    const int tid = threadIdx.x;
    const int lane = tid & 63, wid = tid >> 6;
    const int wm = wid >> 2, wn = wid & 3;     // wave grid 2M x 4N
    const int fr = lane & 15, kg = lane >> 4;
    const int Nm1 = Nreal - 1;
    const int NT = Kd >> 5;                    // K-tiles of 32 (= 12 for K=384)
    f32x4 acc[8][4] = {};

    // loop-invariant frag offsets (u16) within a tile slot
    int offA0[4], offA1[4], offB[4];
#pragma unroll
    for (int m = 0; m < 4; ++m) {
        offA0[m] = foff(wm * 128 + m * 16 + fr, kg);
        offA1[m] = foff(wm * 128 + 64 + m * 16 + fr, kg);
        offB[m]  = foff(wn * 64 + m * 16 + fr, kg);
    }

    // prologue: stage tiles 0,1,2; force tile 0 landed (vmcnt(8) leaves A1,B1,A2,B2)
    STAGE_A(0, 0); STAGE_B(0, 0);
    STAGE_A(1, 1); STAGE_B(1, 1);
    STAGE_A(2, 2); STAGE_B(2, 2);
    asm volatile("s_waitcnt vmcnt(8)" ::: "memory");
    __builtin_amdgcn_s_barrier();

#pragma unroll 4
    for (int t = 0; t < NT; ++t) {
        const int rb = t & 3;
        const u16* la = LA + rb * 8192;
        const u16* lb = LB + rb * 8192;
        bf16x8 af[4], bq[4];
        // ---- phase 1: quad mq0 (wave rows 0-63) ----
#pragma unroll
        for (int m = 0; m < 4; ++m) af[m] = *(const bf16x8*)(la + offA0[m]);
#pragma unroll
        for (int n = 0; n < 4; ++n) bq[n] = *(const bf16x8*)(lb + offB[n]);
        if (t + 3 < NT) STAGE_A((t + 3) & 3, t + 3);
        __builtin_amdgcn_s_barrier();
        __builtin_amdgcn_sched_barrier(0);
        __builtin_amdgcn_s_setprio(1);
#pragma unroll
        for (int m = 0; m < 4; ++m)
#pragma unroll
            for (int n = 0; n < 4; ++n)
                acc[m][n] = __builtin_amdgcn_mfma_f32_16x16x32_bf16(af[m], bq[n], acc[m][n], 0, 0, 0);
        __builtin_amdgcn_s_setprio(0);
        __builtin_amdgcn_sched_barrier(0);
        __builtin_amdgcn_s_barrier();
        // ---- phase 2: quad mq1 (wave rows 64-127), B regs reused ----
        bf16x8 ag[4];
#pragma unroll
        for (int m = 0; m < 4; ++m) ag[m] = *(const bf16x8*)(la + offA1[m]);
        if (t + 3 < NT) STAGE_B((t + 3) & 3, t + 3);
        // counted waits: force tile t+1 landed before its reads next phase-pair.
        if (t < NT - 3)       asm volatile("s_waitcnt vmcnt(6)" ::: "memory");
        else if (t == NT - 3) asm volatile("s_waitcnt vmcnt(4)" ::: "memory");
        else if (t == NT - 2) asm volatile("s_waitcnt vmcnt(0)" ::: "memory");
        __builtin_amdgcn_s_barrier();
        __builtin_amdgcn_sched_barrier(0);
        __builtin_amdgcn_s_setprio(1);
#pragma unroll
        for (int m = 0; m < 4; ++m)
#pragma unroll
            for (int n = 0; n < 4; ++n)
                acc[4 + m][n] = __builtin_amdgcn_mfma_f32_16x16x32_bf16(ag[m], bq[n], acc[4 + m][n], 0, 0, 0);
        __builtin_amdgcn_s_setprio(0);
        __builtin_amdgcn_sched_barrier(0);
        __builtin_amdgcn_s_barrier();
    }

    // epilogue: C/D layout col=lane&15, row=(lane>>4)*4+j [verified m89/m91]
    const int r0 = bm * 256 + wm * 128 + kg * 4;
    const int c0 = bn * 256 + wn * 64 + fr;
#pragma unroll
    for (int m = 0; m < 8; ++m)
#pragma unroll
        for (int n = 0; n < 4; ++n) {
            int col = c0 + n * 16;
            if (col < Nreal) {
#pragma unroll
                for (int j = 0; j < 4; ++j) {
                    size_t off = (size_t)(r0 + m * 16 + j) * Nreal + col;
                    if (OUT_BF16) ((__hip_bfloat16*)Cout)[off] = __float2bfloat16(acc[m][n][j]);
                    else          ((float*)Cout)[off] = acc[m][n][j];
                }
            }
        }
}

// ---------------- fused softmax + collapse to 25 taps ----------------
__global__ __launch_bounds__(256) void attn_w25(const __hip_bfloat16* __restrict__ va,
                                                u16* __restrict__ w25b) {
    int idx = blockIdx.x * 256 + threadIdx.x;
    if (idx >= NPIX * HEADS_) return;
    int pix = idx / 12, h = idx - pix * 12;
    int b = pix / 3136, rs = pix - b * 3136;
    int r = rs / 56, s = rs - r * 56;
    const u16* vap = (const u16*)va;
    float w[25];
#pragma unroll
    for (int t = 0; t < 25; ++t) w[t] = 0.f;
    const float SC = 0.17677669529663687f;  // 1/sqrt(32)
#pragma unroll
    for (int i = 0; i < 3; ++i) {
        int cy = r + 1 - i;
        if ((unsigned)cy >= (unsigned)H_) continue;
#pragma unroll
        for (int j = 0; j < 3; ++j) {
            int cx = s + 1 - j;
            if ((unsigned)cx >= (unsigned)W_) continue;
            const u16* ap = vap + (size_t)(b * 3136 + cy * 56 + cx) * NPAD + C_ + h * 81 + (i * 3 + j) * 9;
            float aq[9];
            float mx = -1e30f;
#pragma unroll
            for (int q = 0; q < 9; ++q) { aq[q] = bf2f(ap[q]); mx = fmaxf(mx, aq[q]); }
            float ssum = 0.f;
#pragma unroll
            for (int q = 0; q < 9; ++q) { aq[q] = __expf((aq[q] - mx) * SC); ssum += aq[q]; }
            float inv = 1.f / ssum;
#pragma unroll
            for (int qi = 0; qi < 3; ++qi)
#pragma unroll
                for (int qj = 0; qj < 3; ++qj)
                    w[(qi - i + 2) * 5 + (qj - j + 2)] += aq[qi * 3 + qj] * inv;
        }
    }
    u16* wp = w25b + (size_t)pix * 300 + h;
#pragma unroll
    for (int t = 0; t < 25; ++t) wp[t * 12] = f2bf(w[t]);
}

// ---------------- fold: y[pix][c] = sum_taps w25[tap][head(c)] * v[tap_pixel][c] ----------------
__global__ __launch_bounds__(384) void fold_gather(const __hip_bfloat16* __restrict__ va,
                                                   const u16* __restrict__ w25b,
                                                   __hip_bfloat16* __restrict__ yb) {
    __shared__ float wls[8][300];
    const int tid = threadIdx.x;
    const int pix0 = blockIdx.x * 8;
    for (int i = tid; i < 2400; i += 384)
        wls[i / 300][i % 300] = bf2f(w25b[(size_t)pix0 * 300 + i]);
    __syncthreads();
    const int g = tid / 48, t = tid - g * 48;
    const int c0 = t * 8, hh = t >> 2;
    const int pix = pix0 + g;
    const int b = pix / 3136, rs = pix - b * 3136;
    const int r = rs / 56, s = rs - r * 56;
    const u16* vap = (const u16*)va;
    float acc[8];
#pragma unroll
    for (int e = 0; e < 8; ++e) acc[e] = 0.f;
    const float* wp = &wls[g][hh];
#pragma unroll
    for (int dy = -2; dy <= 2; ++dy) {
        int py = r + dy;
        if ((unsigned)py >= (unsigned)H_) continue;
#pragma unroll
        for (int dx = -2; dx <= 2; ++dx) {
            int px = s + dx;
            if ((unsigned)px >= (unsigned)W_) continue;
            float w = wp[((dy + 2) * 5 + (dx + 2)) * 12];
            u16x8 v = *(const u16x8*)(vap + (size_t)(b * 3136 + py * 56 + px) * NPAD + c0);
#pragma unroll
            for (int e = 0; e < 8; ++e) acc[e] += w * bf2f(v[e]);
        }
    }
    u16x8 o;
#pragma unroll
    for (int e = 0; e < 8; ++e) o[e] = f2bf(acc[e]);
    *(u16x8*)((u16*)yb + (size_t)pix * C_ + c0) = o;
}

// ---------------- launch ----------------
extern "C" void kernel_launch(void* const* d_in, const int* in_sizes, int n_in,
                              void* d_out, int out_size, void* d_ws, size_t ws_size,
                              hipStream_t stream) {
    const float* x  = (const float*)d_in[0];
    const float* Wv = (const float*)d_in[1];
    const float* Wa = (const float*)d_in[2];
    const float* Wo = (const float*)d_in[3];
    char* ws = (char*)d_ws;
    // ws layout (bytes):
    //   xb/W25b @ 0        : 19267584 (xb dead after gemm1; w25b reuses)
    //   wcat @ 19267584    : 1081344
    //   wob  @ 20348928    : 294912
    //   va   @ 20643840    : 70647808
    //   yb   @ 91291648    : 19267584   (end: 110559232)
    u16*            xb   = (u16*)(ws);
    u16*            w25b = (u16*)(ws);
    __hip_bfloat16* wcat = (__hip_bfloat16*)(ws + 19267584);
    __hip_bfloat16* wob  = (__hip_bfloat16*)(ws + 20348928);
    __hip_bfloat16* va   = (__hip_bfloat16*)(ws + 20643840);
    __hip_bfloat16* yb   = (__hip_bfloat16*)(ws + 91291648);

    hipLaunchKernelGGL(pack_kernel, dim3(2048), dim3(256), 0, stream,
                       x, Wv, Wa, Wo, xb, wcat, wob);

    // gemm1: M=25088 (98 tiles), N=1408 padded to 6x256; B rows clamped, C masked.
    {
        int gridN = 6, nwg = 98 * gridN;  // 588
        int q = nwg / 8, r = nwg % 8;
        hipLaunchKernelGGL(HIP_KERNEL_NAME(gemm256<1>), dim3(nwg), dim3(512), 131072, stream,
                           (const u16*)xb, (const u16*)wcat, (void*)va, NPAD, KDIM, gridN, q, r);
    }
    hipLaunchKernelGGL(attn_w25, dim3((NPIX * HEADS_ + 255) / 256), dim3(256), 0, stream,
                       va, w25b);
    hipLaunchKernelGGL(fold_gather, dim3(NPIX / 8), dim3(384), 0, stream, va, w25b, yb);
    // gemm2: N=384 padded to 2x256 tiles
    {
        int gridN = 2, nwg = 98 * gridN;  // 196
        int q = nwg / 8, r = nwg % 8;
        hipLaunchKernelGGL(HIP_KERNEL_NAME(gemm256<0>), dim3(nwg), dim3(512), 131072, stream,
                           (const u16*)yb, (const u16*)wob, d_out, C_, KDIM, gridN, q, r);
    }
}

// Round 6
// 133.223 us; speedup vs baseline: 1.2292x; 1.1954x over previous
//
#include <hip/hip_runtime.h>
#include <hip/hip_bf16.h>

#define B_ 8
#define H_ 56
#define W_ 56
#define C_ 384
#define HEADS_ 12
#define NPIX (B_*H_*W_)      // 25088
#define NPAD 1408            // 1356 padded to 11*128
#define KDIM 384

typedef unsigned short u16;
typedef __attribute__((ext_vector_type(4))) float f32x4;
typedef __attribute__((ext_vector_type(8))) short bf16x8;
typedef __attribute__((ext_vector_type(8))) unsigned short u16x8;

#define GLDS16(g, l)                                                            \
    __builtin_amdgcn_global_load_lds(                                           \
        (const __attribute__((address_space(1))) void*)(g),                     \
        (__attribute__((address_space(3))) void*)(l), 16, 0, 0)

__device__ __forceinline__ float bf2f(u16 u) {
    union { unsigned int uu; float f; } cv; cv.uu = ((unsigned)u) << 16; return cv.f;
}
__device__ __forceinline__ u16 f2bf(float f) {
    __hip_bfloat16 hb = __float2bfloat16(f);
    return *reinterpret_cast<u16*>(&hb);
}

// ---------------- pack: fp32 -> bf16 (x vectorized, [Wv;Wa;0], Wo) ----------------
__global__ void pack_kernel(const float* __restrict__ x, const float* __restrict__ Wv,
                            const float* __restrict__ Wa, const float* __restrict__ Wo,
                            u16* __restrict__ xb, __hip_bfloat16* __restrict__ wcat,
                            __hip_bfloat16* __restrict__ wob) {
    const int NX8 = NPIX * C_ / 8;   // 1204224 (x in 8-float chunks)
    const int NW = NPAD * KDIM;      // 540672
    const int NO = C_ * C_;          // 147456
    const int total = NX8 + NW + NO;
    for (int idx = blockIdx.x * blockDim.x + threadIdx.x; idx < total;
         idx += gridDim.x * blockDim.x) {
        if (idx < NX8) {
            float4 a = ((const float4*)x)[idx * 2];
            float4 b = ((const float4*)x)[idx * 2 + 1];
            u16x8 o;
            o[0] = f2bf(a.x); o[1] = f2bf(a.y); o[2] = f2bf(a.z); o[3] = f2bf(a.w);
            o[4] = f2bf(b.x); o[5] = f2bf(b.y); o[6] = f2bf(b.z); o[7] = f2bf(b.w);
            ((u16x8*)xb)[idx] = o;
        } else if (idx < NX8 + NW) {
            int t = idx - NX8;
            int o = t / KDIM;
            float v = 0.f;
            if (o < 384) v = Wv[t];
            else if (o < 1356) v = Wa[t - 147456];
            wcat[t] = __float2bfloat16(v);
        } else {
            int t = idx - NX8 - NW;
            wob[t] = __float2bfloat16(Wo[t]);
        }
    }
}

// ---------------- bf16 MFMA GEMM: C[M,N] = A[M,K] * B[N,K]^T ----------------
// R2-verified 128x128/BK=64 structure (0 bank conflicts, XOR row&7 swizzle) +
// minimum-2-phase prefetch: double LDS buffer, STAGE(t+1) issued BEFORE compute(t),
// one drain+barrier per K-tile (T3-min, m248v2). T1 bijective XCD chunk swizzle.

#define STAGE(buf_, kt_) do {                                                        \
    _Pragma("unroll") for (int c = 0; c < 4; ++c) {                                  \
        int rowA = (wid * 4 + c) * 8 + srow;                                         \
        int scol = (sslot ^ (rowA & 7)) * 8;                                         \
        GLDS16(&A[(size_t)(bm * 128 + rowA) * K + (kt_) + scol],                     \
               &As[buf_][(wid * 4 + c) * 512]);                                      \
        GLDS16(&Bw[(size_t)(bn * 128 + rowA) * K + (kt_) + scol],                    \
               &Bs[buf_][(wid * 4 + c) * 512]);                                      \
    } } while (0)

template<int OUT_BF16>
__global__ __launch_bounds__(256) void gemm_bt(const u16* __restrict__ A, const u16* __restrict__ Bw,
                                               void* __restrict__ Cout, int N, int K,
                                               int gridN, int q, int r) {
    __shared__ u16 As[2][128 * 64];
    __shared__ u16 Bs[2][128 * 64];
    const int bid = blockIdx.x;
    const int xcd = bid & 7, ii = bid >> 3;
    const int logical = (xcd < r) ? xcd * (q + 1) + ii : r * (q + 1) + (xcd - r) * q + ii;
    const int bm = logical / gridN, bn = logical - bm * gridN;
    const int tid = threadIdx.x;
    const int lane = tid & 63, wid = tid >> 6;
    const int wm = wid >> 1, wn = wid & 1;
    const int fr = lane & 15;    // fragment row/col within 16
    const int kg = lane >> 4;    // k-group 0..3 (8 contiguous k each)
    const int srow = lane >> 3;  // staging: row-within-8 (0..7)
    const int sslot = lane & 7;  // staging: 16B slot (0..7)
    const int NT = K >> 6;       // 6 for K=384
    f32x4 acc[4][4] = {};

    STAGE(0, 0);
    __syncthreads();
    for (int t = 0; t < NT; ++t) {
        const int cur = t & 1;
        if (t + 1 < NT) STAGE((t + 1) & 1, (t + 1) * 64);   // prefetch next tile
#pragma unroll
        for (int ks = 0; ks < 2; ++ks) {
            bf16x8 af[4], bfr[4];
#pragma unroll
            for (int m = 0; m < 4; ++m) {
                int row = wm * 64 + m * 16 + fr;
                int slot = (ks * 4 + kg) ^ (row & 7);
                af[m] = *(const bf16x8*)(&As[cur][row * 64 + slot * 8]);
            }
#pragma unroll
            for (int n = 0; n < 4; ++n) {
                int row = wn * 64 + n * 16 + fr;
                int slot = (ks * 4 + kg) ^ (row & 7);
                bfr[n] = *(const bf16x8*)(&Bs[cur][row * 64 + slot * 8]);
            }
#pragma unroll
            for (int m = 0; m < 4; ++m)
#pragma unroll
                for (int n = 0; n < 4; ++n)
                    acc[m][n] = __builtin_amdgcn_mfma_f32_16x16x32_bf16(af[m], bfr[n], acc[m][n], 0, 0, 0);
        }
        __syncthreads();   // compiler drains vmcnt here: prefetch had full compute to fly
    }
    // C/D layout: col = lane&15, row = (lane>>4)*4 + j  [verified m89/m91]
    const int r0 = bm * 128 + wm * 64 + kg * 4;
    const int c0 = bn * 128 + wn * 64 + fr;
#pragma unroll
    for (int m = 0; m < 4; ++m)
#pragma unroll
        for (int n = 0; n < 4; ++n)
#pragma unroll
            for (int j = 0; j < 4; ++j) {
                size_t off = (size_t)(r0 + m * 16 + j) * N + (c0 + n * 16);
                if (OUT_BF16) ((__hip_bfloat16*)Cout)[off] = __float2bfloat16(acc[m][n][j]);
                else          ((float*)Cout)[off] = acc[m][n][j];
            }
}

// ---------------- fused softmax+collapse+fold ----------------
// One block per 8-pixel group. Phase A (96 threads): per (pixel,head) softmax over
// 9 centers and collapse to w25[25] -> LDS (fp32, no HBM round-trip).
// Phase B (all 384): 25-tap weighted gather, 8 channels/thread, 16B vector loads.
__global__ __launch_bounds__(384) void attn_fold(const __hip_bfloat16* __restrict__ va,
                                                 __hip_bfloat16* __restrict__ yb) {
    __shared__ float wls[8][300];
    const int tid = threadIdx.x;
    const int pix0 = blockIdx.x * 8;
    const u16* vap = (const u16*)va;

    if (tid < 96) {
        const int pixL = tid / 12, h = tid - pixL * 12;
        const int pix = pix0 + pixL;
        const int b = pix / 3136, rs = pix - b * 3136;
        const int r = rs / 56, s = rs - r * 56;
        float w[25];
#pragma unroll
        for (int t = 0; t < 25; ++t) w[t] = 0.f;
        const float SC = 0.17677669529663687f;  // 1/sqrt(32)
#pragma unroll
        for (int i = 0; i < 3; ++i) {
            int cy = r + 1 - i;
            if ((unsigned)cy >= (unsigned)H_) continue;
#pragma unroll
            for (int j = 0; j < 3; ++j) {
                int cx = s + 1 - j;
                if ((unsigned)cx >= (unsigned)W_) continue;
                const u16* ap = vap + (size_t)(b * 3136 + cy * 56 + cx) * NPAD + C_ + h * 81 + (i * 3 + j) * 9;
                float aq[9];
                float mx = -1e30f;
#pragma unroll
                for (int qq = 0; qq < 9; ++qq) { aq[qq] = bf2f(ap[qq]); mx = fmaxf(mx, aq[qq]); }
                float ssum = 0.f;
#pragma unroll
                for (int qq = 0; qq < 9; ++qq) { aq[qq] = __expf((aq[qq] - mx) * SC); ssum += aq[qq]; }
                float inv = 1.f / ssum;
#pragma unroll
                for (int qi = 0; qi < 3; ++qi)
#pragma unroll
                    for (int qj = 0; qj < 3; ++qj)
                        w[(qi - i + 2) * 5 + (qj - j + 2)] += aq[qi * 3 + qj] * inv;
            }
        }
#pragma unroll
        for (int t = 0; t < 25; ++t) wls[pixL][t * 12 + h] = w[t];
    }
    __syncthreads();

    const int g = tid / 48, t = tid - g * 48;
    const int c0 = t * 8, hh = t >> 2;
    const int pix = pix0 + g;
    const int b = pix / 3136, rs = pix - b * 3136;
    const int r = rs / 56, s = rs - r * 56;
    float acc[8];
#pragma unroll
    for (int e = 0; e < 8; ++e) acc[e] = 0.f;
    const float* wp = &wls[g][hh];
#pragma unroll
    for (int dy = -2; dy <= 2; ++dy) {
        int py = r + dy;
        if ((unsigned)py >= (unsigned)H_) continue;
#pragma unroll
        for (int dx = -2; dx <= 2; ++dx) {
            int px = s + dx;
            if ((unsigned)px >= (unsigned)W_) continue;
            float w = wp[((dy + 2) * 5 + (dx + 2)) * 12];
            u16x8 v = *(const u16x8*)(vap + (size_t)(b * 3136 + py * 56 + px) * NPAD + c0);
#pragma unroll
            for (int e = 0; e < 8; ++e) acc[e] += w * bf2f(v[e]);
        }
    }
    u16x8 o;
#pragma unroll
    for (int e = 0; e < 8; ++e) o[e] = f2bf(acc[e]);
    *(u16x8*)((u16*)yb + (size_t)pix * C_ + c0) = o;
}

// ---------------- launch ----------------
extern "C" void kernel_launch(void* const* d_in, const int* in_sizes, int n_in,
                              void* d_out, int out_size, void* d_ws, size_t ws_size,
                              hipStream_t stream) {
    const float* x  = (const float*)d_in[0];
    const float* Wv = (const float*)d_in[1];
    const float* Wa = (const float*)d_in[2];
    const float* Wo = (const float*)d_in[3];
    char* ws = (char*)d_ws;
    // ws layout (bytes):
    //   xb   @ 0           : 19267584
    //   wcat @ 19267584    : 1081344
    //   wob  @ 20348928    : 294912
    //   va   @ 20643840    : 70647808
    //   yb   @ 91291648    : 19267584   (end: 110559232)
    u16*            xb   = (u16*)(ws);
    __hip_bfloat16* wcat = (__hip_bfloat16*)(ws + 19267584);
    __hip_bfloat16* wob  = (__hip_bfloat16*)(ws + 20348928);
    __hip_bfloat16* va   = (__hip_bfloat16*)(ws + 20643840);
    __hip_bfloat16* yb   = (__hip_bfloat16*)(ws + 91291648);

    hipLaunchKernelGGL(pack_kernel, dim3(2048), dim3(256), 0, stream,
                       x, Wv, Wa, Wo, xb, wcat, wob);

    // gemm1: grid = 196 (M) x 11 (N) = 2156 blocks, XCD-chunked
    {
        int gridN = NPAD / 128, nwg = (NPIX / 128) * gridN;
        int q = nwg / 8, r = nwg % 8;
        hipLaunchKernelGGL(HIP_KERNEL_NAME(gemm_bt<1>), dim3(nwg), dim3(256), 0, stream,
                           (const u16*)xb, (const u16*)wcat, (void*)va, NPAD, KDIM, gridN, q, r);
    }
    hipLaunchKernelGGL(attn_fold, dim3(NPIX / 8), dim3(384), 0, stream, va, yb);
    // gemm2: grid = 196 x 3 = 588 blocks
    {
        int gridN = C_ / 128, nwg = (NPIX / 128) * gridN;
        int q = nwg / 8, r = nwg % 8;
        hipLaunchKernelGGL(HIP_KERNEL_NAME(gemm_bt<0>), dim3(nwg), dim3(256), 0, stream,
                           (const u16*)yb, (const u16*)wob, d_out, C_, KDIM, gridN, q, r);
    }
}